// Round 1
// baseline (1133.386 us; speedup 1.0000x reference)
//
#include <hip/hip_runtime.h>
#include <cstdint>
#include <cstddef>

// Problem constants (match reference)
#define B_    2
#define S_    1024
#define D_    1024
#define E_    8
#define H_    2048
#define TOPK_ 2
#define N_    (B_ * S_)      // 2048 tokens
#define LN_EPS 1e-5f

// ---------------------------------------------------------------------------
// Workspace layout (floats):
//   xn     [N_ * D_]        normalized activations
//   act    [N_*2 * H_]      GLU activations per (token,slot) pair; pair = t*2+slot
//   w_pair [N_*2]           renormalized router weight per pair
//   list   [E_ * N_] (int)  compacted pair ids per expert
//   counts [E_]      (int)  tokens per expert
// Total ~42 MB.
// ---------------------------------------------------------------------------

// ============================ Kernel 1: LN + router =========================
__global__ __launch_bounds__(256) void ln_router_kernel(
    const float* __restrict__ x,
    const float* __restrict__ ln_w,
    const float* __restrict__ ln_b,
    const float* __restrict__ gate_w,
    float* __restrict__ out,        // [N_*D_ residual-init] + [N_*E_ mask]
    float* __restrict__ xn,
    float* __restrict__ w_pair,
    int* __restrict__ list,
    int* __restrict__ counts)
{
    const int t   = blockIdx.x;          // token
    const int tid = threadIdx.x;         // 0..255
    const int wave = tid >> 6, lane = tid & 63;

    __shared__ float rs_[4], rss_[4];
    __shared__ float stats[2];           // mu, rstd
    __shared__ float lred[4][8];

    const float4* xrow = (const float4*)(x + (size_t)t * D_);
    float4 v = xrow[tid];                // 256 * 4 = 1024 elems

    float s  = v.x + v.y + v.z + v.w;
    float ss = v.x*v.x + v.y*v.y + v.z*v.z + v.w*v.w;
    #pragma unroll
    for (int o = 32; o > 0; o >>= 1) { s += __shfl_down(s, o); ss += __shfl_down(ss, o); }
    if (lane == 0) { rs_[wave] = s; rss_[wave] = ss; }
    __syncthreads();
    if (tid == 0) {
        float a = 0.f, b = 0.f;
        #pragma unroll
        for (int i = 0; i < 4; ++i) { a += rs_[i]; b += rss_[i]; }
        float mu = a * (1.f / D_);
        float var = b * (1.f / D_) - mu * mu;
        stats[0] = mu;
        stats[1] = rsqrtf(var + LN_EPS);
    }
    __syncthreads();
    const float mu = stats[0], rstd = stats[1];

    // normalized values for this thread's 4 elements
    const float4 lw = *(const float4*)(ln_w + tid * 4);
    const float4 lb = *(const float4*)(ln_b + tid * 4);
    float4 n;
    n.x = (v.x - mu) * rstd * lw.x + lb.x;
    n.y = (v.y - mu) * rstd * lw.y + lb.y;
    n.z = (v.z - mu) * rstd * lw.z + lb.z;
    n.w = (v.w - mu) * rstd * lw.w + lb.w;

    // write xn and residual init (out = x for now; experts atomically add later)
    *(float4*)(xn + (size_t)t * D_ + tid * 4) = n;
    *(float4*)(out + (size_t)t * D_ + tid * 4) = v;

    // router logits: acc[e] over this thread's 4 elems
    float acc[E_];
    #pragma unroll
    for (int e = 0; e < E_; ++e) {
        const float4 g = *(const float4*)(gate_w + (size_t)e * D_ + tid * 4);
        acc[e] = n.x*g.x + n.y*g.y + n.z*g.z + n.w*g.w;
    }
    #pragma unroll
    for (int e = 0; e < E_; ++e) {
        float r = acc[e];
        #pragma unroll
        for (int o = 32; o > 0; o >>= 1) r += __shfl_down(r, o);
        if (lane == 0) lred[wave][e] = r;
    }
    __syncthreads();

    if (tid == 0) {
        float l[E_];
        #pragma unroll
        for (int e = 0; e < E_; ++e)
            l[e] = lred[0][e] + lred[1][e] + lred[2][e] + lred[3][e];
        // top-2 with lowest-index tie-break (matches jax.lax.top_k)
        int e0 = 0;
        #pragma unroll
        for (int e = 1; e < E_; ++e) if (l[e] > l[e0]) e0 = e;
        int e1 = (e0 == 0) ? 1 : 0;
        #pragma unroll
        for (int e = 0; e < E_; ++e) if (e != e0 && e != e1 && l[e] > l[e1]) e1 = e;
        // renormalized top-2 weights == 2-way softmax (full-softmax denom cancels)
        float m  = l[e0];                 // l[e0] >= l[e1]
        float p0 = 1.f;                   // exp(0)
        float p1 = __expf(l[e1] - m);
        float inv = 1.f / (p0 + p1);
        float w0 = p0 * inv, w1 = p1 * inv;

        float* mask = out + (size_t)N_ * D_ + (size_t)t * E_;
        #pragma unroll
        for (int e = 0; e < E_; ++e)
            mask[e] = (e == e0) ? w0 : ((e == e1) ? w1 : 0.f);

        int i0 = atomicAdd(&counts[e0], 1);
        list[e0 * N_ + i0] = t * 2 + 0;
        int i1 = atomicAdd(&counts[e1], 1);
        list[e1 * N_ + i1] = t * 2 + 1;
        w_pair[t * 2 + 0] = w0;
        w_pair[t * 2 + 1] = w1;
    }
}

// ==================== Kernel 2: per-expert GEMM1 + GLU ======================
// h = xn_gather @ w1[e]  ([cnt,1024] x [1024,4096]); act = gelu(h[:,H:]) * h[:,:H]
// Block tile: 64 rows x 32 act-cols (reads w1 cols c and c+H). 256 thr, 4x2x2 acc.
__global__ __launch_bounds__(256) void gemm1_glu_kernel(
    const float* __restrict__ xn,
    const float* __restrict__ w1,
    const int* __restrict__ list,
    const int* __restrict__ counts,
    float* __restrict__ act)
{
    const int e   = blockIdx.z;
    const int cnt = counts[e];
    const int m0  = blockIdx.y * 64;
    if (m0 >= cnt) return;
    const int c0  = blockIdx.x * 32;

    const float* w1e = w1 + (size_t)e * D_ * (2 * H_);
    const int*   lst = list + e * N_;

    __shared__ int   tok[64];
    __shared__ float As[16][65];        // [k][row], padded
    __shared__ float Bs[2][16][36];     // [half][k][col], padded, 16B-aligned rows

    const int tid = threadIdx.x;
    if (tid < 64) {
        int r = m0 + tid;
        tok[tid] = (r < cnt) ? (lst[r] >> 1) : -1;
    }
    __syncthreads();

    const int ty = tid >> 4, tx = tid & 15;
    float accx[4][2] = {{0.f}}, accg[4][2] = {{0.f}};

    for (int k0 = 0; k0 < D_; k0 += 16) {
        // A: 64 rows x 16 k
        {
            int r  = tid >> 2;
            int kk = (tid & 3) * 4;
            int tk = tok[r];
            float4 a = make_float4(0.f, 0.f, 0.f, 0.f);
            if (tk >= 0) a = *(const float4*)(xn + (size_t)tk * D_ + k0 + kk);
            As[kk + 0][r] = a.x; As[kk + 1][r] = a.y;
            As[kk + 2][r] = a.z; As[kk + 3][r] = a.w;
        }
        // B: 2 halves x 16 k x 32 cols
        {
            int half = tid >> 7;
            int kk   = (tid >> 3) & 15;
            int cc   = (tid & 7) * 4;
            const float* src = w1e + (size_t)(k0 + kk) * (2 * H_) + (half ? (c0 + H_) : c0) + cc;
            *(float4*)&Bs[half][kk][cc] = *(const float4*)src;
        }
        __syncthreads();
        #pragma unroll
        for (int k = 0; k < 16; ++k) {
            float a[4];
            #pragma unroll
            for (int i = 0; i < 4; ++i) a[i] = As[k][ty * 4 + i];
            float bx0 = Bs[0][k][tx * 2], bx1 = Bs[0][k][tx * 2 + 1];
            float bg0 = Bs[1][k][tx * 2], bg1 = Bs[1][k][tx * 2 + 1];
            #pragma unroll
            for (int i = 0; i < 4; ++i) {
                accx[i][0] += a[i] * bx0;  accx[i][1] += a[i] * bx1;
                accg[i][0] += a[i] * bg0;  accg[i][1] += a[i] * bg1;
            }
        }
        __syncthreads();
    }

    #pragma unroll
    for (int i = 0; i < 4; ++i) {
        int r = m0 + ty * 4 + i;
        if (r < cnt) {
            int pair = lst[r];
            float* arow = act + (size_t)pair * H_ + c0 + tx * 2;
            #pragma unroll
            for (int j = 0; j < 2; ++j) {
                float hx = accx[i][j], hg = accg[i][j];
                float g  = 0.5f * hg * (1.f + erff(hg * 0.70710678118f));  // exact gelu
                arow[j]  = g * hx;
            }
        }
    }
}

// ==================== Kernel 3: per-expert GEMM2 + scatter ==================
// out[token] += w_pair * (act[pair] @ w2[e])   ([cnt,2048] x [2048,1024])
// Block tile 64x64, 256 thr, 4x4 acc, atomic scatter epilogue.
__global__ __launch_bounds__(256) void gemm2_kernel(
    const float* __restrict__ act,
    const float* __restrict__ w2,
    const int* __restrict__ list,
    const int* __restrict__ counts,
    const float* __restrict__ w_pair,
    float* __restrict__ out)
{
    const int e   = blockIdx.z;
    const int cnt = counts[e];
    const int m0  = blockIdx.y * 64;
    if (m0 >= cnt) return;
    const int c0  = blockIdx.x * 64;

    const float* w2e = w2 + (size_t)e * H_ * D_;
    const int*   lst = list + e * N_;

    __shared__ int   pr[64];
    __shared__ float wgt[64];
    __shared__ float As[16][65];     // [k][row]
    __shared__ float Bs[16][68];     // [k][col], 68*4=272B row stride (16B aligned)

    const int tid = threadIdx.x;
    if (tid < 64) {
        int r = m0 + tid;
        if (r < cnt) { int p = lst[r]; pr[tid] = p; wgt[tid] = w_pair[p]; }
        else         { pr[tid] = -1;   wgt[tid] = 0.f; }
    }
    __syncthreads();

    const int ty = tid >> 4, tx = tid & 15;
    float acc[4][4] = {{0.f}};

    for (int k0 = 0; k0 < H_; k0 += 16) {
        {
            int r  = tid >> 2;
            int kk = (tid & 3) * 4;
            int p  = pr[r];
            float4 a = make_float4(0.f, 0.f, 0.f, 0.f);
            if (p >= 0) a = *(const float4*)(act + (size_t)p * H_ + k0 + kk);
            As[kk + 0][r] = a.x; As[kk + 1][r] = a.y;
            As[kk + 2][r] = a.z; As[kk + 3][r] = a.w;
        }
        {
            int kk = tid >> 4;          // 0..15
            int cc = (tid & 15) * 4;    // 0..60
            *(float4*)&Bs[kk][cc] = *(const float4*)(w2e + (size_t)(k0 + kk) * D_ + c0 + cc);
        }
        __syncthreads();
        #pragma unroll
        for (int k = 0; k < 16; ++k) {
            float a[4];
            #pragma unroll
            for (int i = 0; i < 4; ++i) a[i] = As[k][ty * 4 + i];
            float4 b = *(float4*)&Bs[k][tx * 4];
            #pragma unroll
            for (int i = 0; i < 4; ++i) {
                acc[i][0] += a[i] * b.x; acc[i][1] += a[i] * b.y;
                acc[i][2] += a[i] * b.z; acc[i][3] += a[i] * b.w;
            }
        }
        __syncthreads();
    }

    #pragma unroll
    for (int i = 0; i < 4; ++i) {
        int r = m0 + ty * 4 + i;
        if (r < cnt) {
            int p = pr[ty * 4 + i];
            int token = p >> 1;
            float w = wgt[ty * 4 + i];
            float* orow = out + (size_t)token * D_ + c0 + tx * 4;
            #pragma unroll
            for (int j = 0; j < 4; ++j) atomicAdd(&orow[j], w * acc[i][j]);
        }
    }
}

// =============================== launcher ===================================
extern "C" void kernel_launch(void* const* d_in, const int* in_sizes, int n_in,
                              void* d_out, int out_size, void* d_ws, size_t ws_size,
                              hipStream_t stream)
{
    const float* x      = (const float*)d_in[0];
    const float* ln_w   = (const float*)d_in[1];
    const float* ln_b   = (const float*)d_in[2];
    const float* gate_w = (const float*)d_in[3];
    const float* w1     = (const float*)d_in[4];
    const float* w2     = (const float*)d_in[5];
    float* out = (float*)d_out;

    // workspace carve (~42 MB)
    float* ws     = (float*)d_ws;
    float* xn     = ws;                                   // N_*D_
    float* act    = xn + (size_t)N_ * D_;                 // N_*2*H_
    float* w_pair = act + (size_t)N_ * 2 * H_;            // N_*2
    int*   list   = (int*)(w_pair + (size_t)N_ * 2);      // E_*N_
    int*   counts = list + E_ * N_;                       // E_

    hipMemsetAsync(counts, 0, E_ * sizeof(int), stream);

    ln_router_kernel<<<N_, 256, 0, stream>>>(x, ln_w, ln_b, gate_w, out, xn,
                                             w_pair, list, counts);

    dim3 g1(H_ / 32, N_ / 64, E_);   // 64 x 32 x 8
    gemm1_glu_kernel<<<g1, 256, 0, stream>>>(xn, w1, list, counts, act);

    dim3 g2(D_ / 64, N_ / 64, E_);   // 16 x 32 x 8
    gemm2_kernel<<<g2, 256, 0, stream>>>(act, w2, list, counts, w_pair, out);
}

// Round 2
// 437.690 us; speedup vs baseline: 2.5895x; 2.5895x over previous
//
#include <hip/hip_runtime.h>
#include <cstdint>
#include <cstddef>

#define B_    2
#define S_    1024
#define D_    1024
#define E_    8
#define H_    2048
#define H2_   (2*H_)
#define N_    (B_*S_)
#define LN_EPS 1e-5f

typedef __attribute__((ext_vector_type(8))) short bf16x8;
typedef __attribute__((ext_vector_type(4))) float f32x4;
typedef __attribute__((ext_vector_type(4))) unsigned short u16x4;

__device__ __forceinline__ unsigned short f2bf(float f) {
    union { float f; unsigned u; } v; v.f = f;
    unsigned r = v.u + 0x7FFFu + ((v.u >> 16) & 1u);   // RNE
    return (unsigned short)(r >> 16);
}
__device__ __forceinline__ float gelu_exact(float g) {
    return 0.5f * g * (1.f + erff(g * 0.70710678118654752f));
}
__device__ __forceinline__ float f4i(const float4& v, int i) { return (&v.x)[i]; }

// ============================ Kernel 1: LN + router =========================
__global__ __launch_bounds__(256) void ln_router_kernel(
    const float* __restrict__ x,
    const float* __restrict__ ln_w,
    const float* __restrict__ ln_b,
    const float* __restrict__ gate_w,
    float* __restrict__ out,
    unsigned short* __restrict__ xn_b,
    float* __restrict__ w_pair,
    int* __restrict__ list,
    int* __restrict__ counts)
{
    const int t   = blockIdx.x;
    const int tid = threadIdx.x;
    const int wave = tid >> 6, lane = tid & 63;

    __shared__ float rs_[4], rss_[4];
    __shared__ float stats[2];
    __shared__ float lred[4][8];

    const float4* xrow = (const float4*)(x + (size_t)t * D_);
    float4 v = xrow[tid];

    float s  = v.x + v.y + v.z + v.w;
    float ss = v.x*v.x + v.y*v.y + v.z*v.z + v.w*v.w;
    #pragma unroll
    for (int o = 32; o > 0; o >>= 1) { s += __shfl_down(s, o); ss += __shfl_down(ss, o); }
    if (lane == 0) { rs_[wave] = s; rss_[wave] = ss; }
    __syncthreads();
    if (tid == 0) {
        float a = 0.f, b = 0.f;
        #pragma unroll
        for (int i = 0; i < 4; ++i) { a += rs_[i]; b += rss_[i]; }
        float mu = a * (1.f / D_);
        float var = b * (1.f / D_) - mu * mu;
        stats[0] = mu;
        stats[1] = rsqrtf(var + LN_EPS);
    }
    __syncthreads();
    const float mu = stats[0], rstd = stats[1];

    const float4 lw = *(const float4*)(ln_w + tid * 4);
    const float4 lb = *(const float4*)(ln_b + tid * 4);
    float4 n;
    n.x = (v.x - mu) * rstd * lw.x + lb.x;
    n.y = (v.y - mu) * rstd * lw.y + lb.y;
    n.z = (v.z - mu) * rstd * lw.z + lb.z;
    n.w = (v.w - mu) * rstd * lw.w + lb.w;

    u16x4 nb = { f2bf(n.x), f2bf(n.y), f2bf(n.z), f2bf(n.w) };
    *(u16x4*)(xn_b + (size_t)t * D_ + tid * 4) = nb;
    *(float4*)(out + (size_t)t * D_ + tid * 4) = v;   // residual init

    float acc[E_];
    #pragma unroll
    for (int e = 0; e < E_; ++e) {
        const float4 g = *(const float4*)(gate_w + (size_t)e * D_ + tid * 4);
        acc[e] = n.x*g.x + n.y*g.y + n.z*g.z + n.w*g.w;
    }
    #pragma unroll
    for (int e = 0; e < E_; ++e) {
        float r = acc[e];
        #pragma unroll
        for (int o = 32; o > 0; o >>= 1) r += __shfl_down(r, o);
        if (lane == 0) lred[wave][e] = r;
    }
    __syncthreads();

    if (tid == 0) {
        float l[E_];
        #pragma unroll
        for (int e = 0; e < E_; ++e)
            l[e] = lred[0][e] + lred[1][e] + lred[2][e] + lred[3][e];
        int e0 = 0;
        #pragma unroll
        for (int e = 1; e < E_; ++e) if (l[e] > l[e0]) e0 = e;
        int e1 = (e0 == 0) ? 1 : 0;
        #pragma unroll
        for (int e = 0; e < E_; ++e) if (e != e0 && e != e1 && l[e] > l[e1]) e1 = e;
        float m  = l[e0];
        float p1 = __expf(l[e1] - m);
        float inv = 1.f / (1.f + p1);
        float w0 = inv, w1 = p1 * inv;

        float* mask = out + (size_t)N_ * D_ + (size_t)t * E_;
        #pragma unroll
        for (int e = 0; e < E_; ++e)
            mask[e] = (e == e0) ? w0 : ((e == e1) ? w1 : 0.f);

        int i0 = atomicAdd(&counts[e0], 1);
        list[e0 * N_ + i0] = t * 2 + 0;
        int i1 = atomicAdd(&counts[e1], 1);
        list[e1 * N_ + i1] = t * 2 + 1;
        w_pair[t * 2 + 0] = w0;
        w_pair[t * 2 + 1] = w1;
    }
}

// ================= Weight prep: [R][C] fp32 -> [C][R] bf16 ==================
__global__ __launch_bounds__(256) void wprep_kernel(
    const float* __restrict__ src, unsigned short* __restrict__ dst,
    int R, int C)
{
    const int e = blockIdx.z;
    src += (size_t)e * R * C;
    dst += (size_t)e * R * C;
    const int r0 = blockIdx.y * 64, c0 = blockIdx.x * 64;
    __shared__ unsigned short T[64][72];
    const int tid = threadIdx.x;
    const int kk = tid >> 4;
    const int cc = (tid & 15) * 4;
    #pragma unroll
    for (int s = 0; s < 4; ++s) {
        int k = kk + s * 16;
        const float4 v = *(const float4*)(src + (size_t)(r0 + k) * C + c0 + cc);
        T[cc + 0][k] = f2bf(v.x);
        T[cc + 1][k] = f2bf(v.y);
        T[cc + 2][k] = f2bf(v.z);
        T[cc + 3][k] = f2bf(v.w);
    }
    __syncthreads();
    const int c  = tid >> 2;
    const int k4 = (tid & 3) * 16;
    bf16x8 lo = *(const bf16x8*)&T[c][k4];
    bf16x8 hi = *(const bf16x8*)&T[c][k4 + 8];
    unsigned short* o = dst + (size_t)(c0 + c) * R + r0 + k4;
    *(bf16x8*)o = lo;
    *(bf16x8*)(o + 8) = hi;
}

// ==================== Kernel 2: GEMM1 (MFMA bf16) + GLU =====================
// tile: 128 rows x (128 x-cols + 128 gate-cols), BK=32; 4 waves 2x2, wave=64x(64+64)
template<bool PRET>
__global__ __launch_bounds__(256, 2) void gemm1_kernel(
    const unsigned short* __restrict__ xn_b,
    const float* __restrict__ w1,            // [E][D][2H] fp32 (fallback)
    const unsigned short* __restrict__ w1t,  // [E][2H][D] bf16 (PRET)
    const int* __restrict__ list,
    const int* __restrict__ counts,
    unsigned short* __restrict__ act_b)
{
    const int e = blockIdx.z;
    const int cnt = counts[e];
    const int m0 = blockIdx.y * 128;
    if (m0 >= cnt) return;
    const int c0 = blockIdx.x * 128;

    __shared__ unsigned short As[128][40];
    __shared__ unsigned short Bs[256][40];   // rows 0..127 = x cols, 128..255 = gate
    __shared__ int pairL[128];

    const int tid  = threadIdx.x;
    const int lane = tid & 63;
    const int wv   = tid >> 6;
    const int wr   = wv >> 1, wc = wv & 1;
    const int* lst = list + e * N_;

    if (tid < 128) {
        int r = m0 + tid;
        pairL[tid] = (r < cnt) ? lst[r] : -1;
    }
    __syncthreads();

    const int sr  = tid >> 2;         // 0..63
    const int skk = (tid & 3) * 8;    // 0,8,16,24

    const unsigned short* aSrc[2];
    #pragma unroll
    for (int i = 0; i < 2; ++i) {
        int p = pairL[i * 64 + sr];
        int tok = (p >= 0) ? (p >> 1) : 0;
        aSrc[i] = xn_b + (size_t)tok * D_ + skk;
    }

    const unsigned short* bSrcT[4];
    const float* bFsrc[2];
    int bCgl[2];
    if constexpr (PRET) {
        const unsigned short* w1te = w1t + (size_t)e * D_ * H2_;
        #pragma unroll
        for (int i = 0; i < 4; ++i) {
            int br = i * 64 + sr;
            int gcol = (br < 128) ? (c0 + br) : (H_ + c0 + br - 128);
            bSrcT[i] = w1te + (size_t)gcol * D_ + skk;
        }
    } else {
        const float* w1e = w1 + (size_t)e * D_ * H2_;
        #pragma unroll
        for (int u = 0; u < 2; ++u) {
            int idx = tid * 2 + u;
            int cg = idx & 63, kg = idx >> 6;         // cg: 4-col group, kg: 4-k group
            int cgl = cg * 4;
            int gcol = (cgl < 128) ? (c0 + cgl) : (H_ + c0 + cgl - 128);
            bFsrc[u] = w1e + (size_t)(kg * 4) * H2_ + gcol;
            bCgl[u] = cgl | (kg << 16);
        }
    }

    // prefetch k0=0
    bf16x8 aR[2], bR[4];
    float4 bF[2][4];
    #pragma unroll
    for (int i = 0; i < 2; ++i) aR[i] = *(const bf16x8*)(aSrc[i]);
    if constexpr (PRET) {
        #pragma unroll
        for (int i = 0; i < 4; ++i) bR[i] = *(const bf16x8*)(bSrcT[i]);
    } else {
        #pragma unroll
        for (int u = 0; u < 2; ++u)
            #pragma unroll
            for (int j = 0; j < 4; ++j)
                bF[u][j] = *(const float4*)(bFsrc[u] + (size_t)j * H2_);
    }

    f32x4 accx[4][4], accg[4][4];
    #pragma unroll
    for (int m = 0; m < 4; ++m)
        #pragma unroll
        for (int n = 0; n < 4; ++n) {
            accx[m][n] = (f32x4){0.f, 0.f, 0.f, 0.f};
            accg[m][n] = (f32x4){0.f, 0.f, 0.f, 0.f};
        }

    const int fr = lane & 15, fg = (lane >> 4) * 8;

    for (int k0 = 0; k0 < D_; k0 += 32) {
        __syncthreads();
        #pragma unroll
        for (int i = 0; i < 2; ++i) *(bf16x8*)&As[i * 64 + sr][skk] = aR[i];
        if constexpr (PRET) {
            #pragma unroll
            for (int i = 0; i < 4; ++i) *(bf16x8*)&Bs[i * 64 + sr][skk] = bR[i];
        } else {
            #pragma unroll
            for (int u = 0; u < 2; ++u) {
                int cgl = bCgl[u] & 0xFFFF, kg = bCgl[u] >> 16;
                #pragma unroll
                for (int i = 0; i < 4; ++i) {
                    u16x4 pk = { f2bf(f4i(bF[u][0], i)), f2bf(f4i(bF[u][1], i)),
                                 f2bf(f4i(bF[u][2], i)), f2bf(f4i(bF[u][3], i)) };
                    *(u16x4*)&Bs[cgl + i][kg * 4] = pk;
                }
            }
        }
        __syncthreads();

        if (k0 + 32 < D_) {
            int kn = k0 + 32;
            #pragma unroll
            for (int i = 0; i < 2; ++i) aR[i] = *(const bf16x8*)(aSrc[i] + kn);
            if constexpr (PRET) {
                #pragma unroll
                for (int i = 0; i < 4; ++i) bR[i] = *(const bf16x8*)(bSrcT[i] + kn);
            } else {
                #pragma unroll
                for (int u = 0; u < 2; ++u)
                    #pragma unroll
                    for (int j = 0; j < 4; ++j)
                        bF[u][j] = *(const float4*)(bFsrc[u] + (size_t)(kn + j) * H2_);
            }
        }

        bf16x8 af[4];
        #pragma unroll
        for (int m = 0; m < 4; ++m) af[m] = *(const bf16x8*)&As[wr * 64 + m * 16 + fr][fg];
        {
            bf16x8 bxf[4];
            #pragma unroll
            for (int n = 0; n < 4; ++n) bxf[n] = *(const bf16x8*)&Bs[wc * 64 + n * 16 + fr][fg];
            #pragma unroll
            for (int m = 0; m < 4; ++m)
                #pragma unroll
                for (int n = 0; n < 4; ++n)
                    accx[m][n] = __builtin_amdgcn_mfma_f32_16x16x32_bf16(af[m], bxf[n], accx[m][n], 0, 0, 0);
        }
        {
            bf16x8 bgf[4];
            #pragma unroll
            for (int n = 0; n < 4; ++n) bgf[n] = *(const bf16x8*)&Bs[128 + wc * 64 + n * 16 + fr][fg];
            #pragma unroll
            for (int m = 0; m < 4; ++m)
                #pragma unroll
                for (int n = 0; n < 4; ++n)
                    accg[m][n] = __builtin_amdgcn_mfma_f32_16x16x32_bf16(af[m], bgf[n], accg[m][n], 0, 0, 0);
        }
    }

    const int fq = lane >> 4;
    #pragma unroll
    for (int m = 0; m < 4; ++m) {
        #pragma unroll
        for (int j = 0; j < 4; ++j) {
            int rowt = wr * 64 + m * 16 + fq * 4 + j;
            if (m0 + rowt < cnt) {
                int pair = pairL[rowt];
                unsigned short* arow = act_b + (size_t)pair * H_ + c0 + wc * 64 + fr;
                #pragma unroll
                for (int n = 0; n < 4; ++n) {
                    float hx = accx[m][n][j];
                    float hg = accg[m][n][j];
                    arow[n * 16] = f2bf(gelu_exact(hg) * hx);
                }
            }
        }
    }
}

// ==================== Kernel 3: GEMM2 (MFMA bf16) + scatter =================
// tile 128x128, BK=32, K split in 2; 4 waves 2x2, wave=64x64
template<bool PRET>
__global__ __launch_bounds__(256, 2) void gemm2_kernel(
    const unsigned short* __restrict__ act_b,
    const float* __restrict__ w2,            // [E][H][D] fp32 (fallback)
    const unsigned short* __restrict__ w2t,  // [E][D][H] bf16 (PRET)
    const int* __restrict__ list,
    const int* __restrict__ counts,
    const float* __restrict__ w_pair,
    float* __restrict__ out)
{
    const int z = blockIdx.z;
    const int e = z >> 1, ks = z & 1;
    const int cnt = counts[e];
    const int m0 = blockIdx.y * 128;
    if (m0 >= cnt) return;
    const int c0 = blockIdx.x * 128;
    const int kbeg = ks * (H_ / 2), kend = kbeg + H_ / 2;

    __shared__ unsigned short As[128][40];
    __shared__ unsigned short Bs[128][40];
    __shared__ int   pairL[128];
    __shared__ float wgtL[128];

    const int tid  = threadIdx.x;
    const int lane = tid & 63;
    const int wv   = tid >> 6;
    const int wr   = wv >> 1, wc = wv & 1;
    const int* lst = list + e * N_;

    if (tid < 128) {
        int r = m0 + tid;
        int p = (r < cnt) ? lst[r] : -1;
        pairL[tid] = p;
        wgtL[tid]  = (p >= 0) ? w_pair[p] : 0.f;
    }
    __syncthreads();

    const int sr  = tid >> 2;
    const int skk = (tid & 3) * 8;

    const unsigned short* aSrc[2];
    #pragma unroll
    for (int i = 0; i < 2; ++i) {
        int p = pairL[i * 64 + sr];
        aSrc[i] = act_b + (size_t)((p >= 0) ? p : 0) * H_ + skk;
    }

    const unsigned short* bSrcT[2];
    const float* bFsrc;
    int bCg = 0, bKg = 0;
    if constexpr (PRET) {
        const unsigned short* w2te = w2t + (size_t)e * D_ * H_;
        #pragma unroll
        for (int i = 0; i < 2; ++i)
            bSrcT[i] = w2te + (size_t)(c0 + i * 64 + sr) * H_ + skk;
    } else {
        const float* w2e = w2 + (size_t)e * H_ * D_;
        bCg = (tid & 31) * 4;       // local col
        bKg = (tid >> 5) * 4;       // local k
        bFsrc = w2e + (size_t)bKg * D_ + c0 + bCg;
    }

    bf16x8 aR[2], bR[2];
    float4 bF[4];
    #pragma unroll
    for (int i = 0; i < 2; ++i) aR[i] = *(const bf16x8*)(aSrc[i] + kbeg);
    if constexpr (PRET) {
        #pragma unroll
        for (int i = 0; i < 2; ++i) bR[i] = *(const bf16x8*)(bSrcT[i] + kbeg);
    } else {
        #pragma unroll
        for (int j = 0; j < 4; ++j) bF[j] = *(const float4*)(bFsrc + (size_t)(kbeg + j) * D_);
    }

    f32x4 acc[4][4];
    #pragma unroll
    for (int m = 0; m < 4; ++m)
        #pragma unroll
        for (int n = 0; n < 4; ++n) acc[m][n] = (f32x4){0.f, 0.f, 0.f, 0.f};

    const int fr = lane & 15, fg = (lane >> 4) * 8;

    for (int k0 = kbeg; k0 < kend; k0 += 32) {
        __syncthreads();
        #pragma unroll
        for (int i = 0; i < 2; ++i) *(bf16x8*)&As[i * 64 + sr][skk] = aR[i];
        if constexpr (PRET) {
            #pragma unroll
            for (int i = 0; i < 2; ++i) *(bf16x8*)&Bs[i * 64 + sr][skk] = bR[i];
        } else {
            #pragma unroll
            for (int i = 0; i < 4; ++i) {
                u16x4 pk = { f2bf(f4i(bF[0], i)), f2bf(f4i(bF[1], i)),
                             f2bf(f4i(bF[2], i)), f2bf(f4i(bF[3], i)) };
                *(u16x4*)&Bs[bCg + i][bKg] = pk;
            }
        }
        __syncthreads();

        if (k0 + 32 < kend) {
            int kn = k0 + 32;
            #pragma unroll
            for (int i = 0; i < 2; ++i) aR[i] = *(const bf16x8*)(aSrc[i] + kn);
            if constexpr (PRET) {
                #pragma unroll
                for (int i = 0; i < 2; ++i) bR[i] = *(const bf16x8*)(bSrcT[i] + kn);
            } else {
                #pragma unroll
                for (int j = 0; j < 4; ++j) bF[j] = *(const float4*)(bFsrc + (size_t)(kn + j) * D_);
            }
        }

        bf16x8 af[4], bf_[4];
        #pragma unroll
        for (int m = 0; m < 4; ++m) af[m] = *(const bf16x8*)&As[wr * 64 + m * 16 + fr][fg];
        #pragma unroll
        for (int n = 0; n < 4; ++n) bf_[n] = *(const bf16x8*)&Bs[wc * 64 + n * 16 + fr][fg];
        #pragma unroll
        for (int m = 0; m < 4; ++m)
            #pragma unroll
            for (int n = 0; n < 4; ++n)
                acc[m][n] = __builtin_amdgcn_mfma_f32_16x16x32_bf16(af[m], bf_[n], acc[m][n], 0, 0, 0);
    }

    const int fq = lane >> 4;
    #pragma unroll
    for (int m = 0; m < 4; ++m) {
        #pragma unroll
        for (int j = 0; j < 4; ++j) {
            int rowt = wr * 64 + m * 16 + fq * 4 + j;
            if (m0 + rowt < cnt) {
                int p = pairL[rowt];
                int token = p >> 1;
                float w = wgtL[rowt];
                float* orow = out + (size_t)token * D_ + c0 + wc * 64 + fr;
                #pragma unroll
                for (int n = 0; n < 4; ++n)
                    atomicAdd(&orow[n * 16], w * acc[m][n][j]);
            }
        }
    }
}

// =============================== launcher ===================================
extern "C" void kernel_launch(void* const* d_in, const int* in_sizes, int n_in,
                              void* d_out, int out_size, void* d_ws, size_t ws_size,
                              hipStream_t stream)
{
    const float* x      = (const float*)d_in[0];
    const float* ln_w   = (const float*)d_in[1];
    const float* ln_b   = (const float*)d_in[2];
    const float* gate_w = (const float*)d_in[3];
    const float* w1     = (const float*)d_in[4];
    const float* w2     = (const float*)d_in[5];
    float* out = (float*)d_out;

    unsigned char* w = (unsigned char*)d_ws;
    size_t off = 0;
    auto alloc = [&](size_t bytes) -> void* {
        void* p = w + off;
        off += (bytes + 255) & ~(size_t)255;
        return p;
    };
    unsigned short* xn_b  = (unsigned short*)alloc((size_t)N_ * D_ * 2);
    unsigned short* act_b = (unsigned short*)alloc((size_t)N_ * 2 * H_ * 2);
    float* w_pair = (float*)alloc((size_t)N_ * 2 * 4);
    int*   lists  = (int*)alloc((size_t)E_ * N_ * 4);
    int*   counts = (int*)alloc(256);
    unsigned short* w1t = (unsigned short*)alloc((size_t)E_ * D_ * H2_ * 2);
    unsigned short* w2t = (unsigned short*)alloc((size_t)E_ * H_ * D_ * 2);
    const bool pret = (ws_size >= off);

    hipMemsetAsync(counts, 0, 256, stream);

    if (pret) {
        wprep_kernel<<<dim3(H2_ / 64, D_ / 64, E_), 256, 0, stream>>>(w1, w1t, D_, H2_);
        wprep_kernel<<<dim3(D_ / 64, H_ / 64, E_), 256, 0, stream>>>(w2, w2t, H_, D_);
    }

    ln_router_kernel<<<N_, 256, 0, stream>>>(x, ln_w, ln_b, gate_w, out, xn_b,
                                             w_pair, lists, counts);

    if (pret) {
        gemm1_kernel<true><<<dim3(H_ / 128, 16, E_), 256, 0, stream>>>(
            xn_b, w1, w1t, lists, counts, act_b);
        gemm2_kernel<true><<<dim3(D_ / 128, 16, E_ * 2), 256, 0, stream>>>(
            act_b, w2, w2t, lists, counts, w_pair, out);
    } else {
        gemm1_kernel<false><<<dim3(H_ / 128, 16, E_), 256, 0, stream>>>(
            xn_b, w1, w1t, lists, counts, act_b);
        gemm2_kernel<false><<<dim3(D_ / 128, 16, E_ * 2), 256, 0, stream>>>(
            act_b, w2, w2t, lists, counts, w_pair, out);
    }
}

// Round 6
// 434.178 us; speedup vs baseline: 2.6104x; 1.0081x over previous
//
#include <hip/hip_runtime.h>
#include <cstdint>
#include <cstddef>

#define B_    2
#define S_    1024
#define D_    1024
#define E_    8
#define H_    2048
#define H2_   (2*H_)
#define N_    (B_*S_)
#define LN_EPS 1e-5f

typedef __attribute__((ext_vector_type(8))) short bf16x8;
typedef __attribute__((ext_vector_type(4))) float f32x4;
typedef __attribute__((ext_vector_type(4))) unsigned short u16x4;

__device__ __forceinline__ unsigned short f2bf(float f) {
    union { float f; unsigned u; } v; v.f = f;
    unsigned r = v.u + 0x7FFFu + ((v.u >> 16) & 1u);   // RNE
    return (unsigned short)(r >> 16);
}
__device__ __forceinline__ float gelu_exact(float g) {
    return 0.5f * g * (1.f + erff(g * 0.70710678118654752f));
}
// async 16B global->LDS (lds ptr must be wave-uniform; HW adds lane*16)
__device__ __forceinline__ void gl16(const void* g, void* l) {
    __builtin_amdgcn_global_load_lds(
        (const __attribute__((address_space(1))) unsigned int*)g,
        (__attribute__((address_space(3))) unsigned int*)l, 16, 0, 0);
}

// ============================ Kernel 1: LN + router =========================
__global__ __launch_bounds__(256) void ln_router_kernel(
    const float* __restrict__ x,
    const float* __restrict__ ln_w,
    const float* __restrict__ ln_b,
    const float* __restrict__ gate_w,
    float* __restrict__ out,
    unsigned short* __restrict__ xn_b,
    float* __restrict__ w_pair,
    int* __restrict__ list,
    int* __restrict__ counts)
{
    const int t   = blockIdx.x;
    const int tid = threadIdx.x;
    const int wave = tid >> 6, lane = tid & 63;

    __shared__ float rs_[4], rss_[4];
    __shared__ float stats[2];
    __shared__ float lred[4][8];

    const float4* xrow = (const float4*)(x + (size_t)t * D_);
    float4 v = xrow[tid];

    float s  = v.x + v.y + v.z + v.w;
    float ss = v.x*v.x + v.y*v.y + v.z*v.z + v.w*v.w;
    #pragma unroll
    for (int o = 32; o > 0; o >>= 1) { s += __shfl_down(s, o); ss += __shfl_down(ss, o); }
    if (lane == 0) { rs_[wave] = s; rss_[wave] = ss; }
    __syncthreads();
    if (tid == 0) {
        float a = 0.f, b = 0.f;
        #pragma unroll
        for (int i = 0; i < 4; ++i) { a += rs_[i]; b += rss_[i]; }
        float mu = a * (1.f / D_);
        float var = b * (1.f / D_) - mu * mu;
        stats[0] = mu;
        stats[1] = rsqrtf(var + LN_EPS);
    }
    __syncthreads();
    const float mu = stats[0], rstd = stats[1];

    const float4 lw = *(const float4*)(ln_w + tid * 4);
    const float4 lb = *(const float4*)(ln_b + tid * 4);
    float4 n;
    n.x = (v.x - mu) * rstd * lw.x + lb.x;
    n.y = (v.y - mu) * rstd * lw.y + lb.y;
    n.z = (v.z - mu) * rstd * lw.z + lb.z;
    n.w = (v.w - mu) * rstd * lw.w + lb.w;

    u16x4 nb = { f2bf(n.x), f2bf(n.y), f2bf(n.z), f2bf(n.w) };
    *(u16x4*)(xn_b + (size_t)t * D_ + tid * 4) = nb;
    *(float4*)(out + (size_t)t * D_ + tid * 4) = v;   // residual init

    float acc[E_];
    #pragma unroll
    for (int e = 0; e < E_; ++e) {
        const float4 g = *(const float4*)(gate_w + (size_t)e * D_ + tid * 4);
        acc[e] = n.x*g.x + n.y*g.y + n.z*g.z + n.w*g.w;
    }
    #pragma unroll
    for (int e = 0; e < E_; ++e) {
        float r = acc[e];
        #pragma unroll
        for (int o = 32; o > 0; o >>= 1) r += __shfl_down(r, o);
        if (lane == 0) lred[wave][e] = r;
    }
    __syncthreads();

    if (tid == 0) {
        float l[E_];
        #pragma unroll
        for (int e = 0; e < E_; ++e)
            l[e] = lred[0][e] + lred[1][e] + lred[2][e] + lred[3][e];
        int e0 = 0;
        #pragma unroll
        for (int e = 1; e < E_; ++e) if (l[e] > l[e0]) e0 = e;
        int e1 = (e0 == 0) ? 1 : 0;
        #pragma unroll
        for (int e = 0; e < E_; ++e) if (e != e0 && e != e1 && l[e] > l[e1]) e1 = e;
        float m  = l[e0];
        float p1 = __expf(l[e1] - m);
        float inv = 1.f / (1.f + p1);
        float w0 = inv, w1 = p1 * inv;

        float* mask = out + (size_t)N_ * D_ + (size_t)t * E_;
        #pragma unroll
        for (int e = 0; e < E_; ++e)
            mask[e] = (e == e0) ? w0 : ((e == e1) ? w1 : 0.f);

        int i0 = atomicAdd(&counts[e0], 1);
        list[e0 * N_ + i0] = t * 2 + 0;
        int i1 = atomicAdd(&counts[e1], 1);
        list[e1 * N_ + i1] = t * 2 + 1;
        w_pair[t * 2 + 0] = w0;
        w_pair[t * 2 + 1] = w1;
    }
}

// ====== Weight prep (merged): [R][C] fp32 -> [C][R] bf16 for w1 and w2 ======
__global__ __launch_bounds__(256) void wprep_kernel(
    const float* __restrict__ w1, const float* __restrict__ w2,
    unsigned short* __restrict__ w1t, unsigned short* __restrict__ w2t)
{
    const int bid = blockIdx.x;
    const float* src; unsigned short* dst; int R, C, r0, c0;
    if (bid < 8192) {                       // w1: per-e R=D rows, C=2H cols
        int e = bid >> 10, t = bid & 1023;  // 16 r-tiles x 64 c-tiles
        R = D_; C = H2_;
        src = w1  + (size_t)e * R * C;
        dst = w1t + (size_t)e * R * C;
        r0 = (t & 15) * 64; c0 = (t >> 4) * 64;
    } else {                                // w2: per-e R=H rows, C=D cols
        int b2 = bid - 8192;
        int e = b2 >> 9, t = b2 & 511;      // 32 r-tiles x 16 c-tiles
        R = H_; C = D_;
        src = w2  + (size_t)e * R * C;
        dst = w2t + (size_t)e * R * C;
        r0 = (t & 31) * 64; c0 = (t >> 5) * 64;
    }

    __shared__ unsigned short T[64][72];
    const int tid = threadIdx.x;
    const int kk = tid >> 4;
    const int cc = (tid & 15) * 4;
    #pragma unroll
    for (int s = 0; s < 4; ++s) {
        int k = kk + s * 16;
        const float4 v = *(const float4*)(src + (size_t)(r0 + k) * C + c0 + cc);
        T[cc + 0][k] = f2bf(v.x);
        T[cc + 1][k] = f2bf(v.y);
        T[cc + 2][k] = f2bf(v.z);
        T[cc + 3][k] = f2bf(v.w);
    }
    __syncthreads();
    const int c  = tid >> 2;
    const int k4 = (tid & 3) * 16;
    bf16x8 lo = *(const bf16x8*)&T[c][k4];
    bf16x8 hi = *(const bf16x8*)&T[c][k4 + 8];
    unsigned short* o = dst + (size_t)(c0 + c) * R + r0 + k4;
    *(bf16x8*)o = lo;
    *(bf16x8*)(o + 8) = hi;
}

// ==================== Kernel 2: GEMM1 (MFMA bf16) + GLU =====================
// Block: 128 rows x 64 act-cols (reads 64 x-cols + 64 gate-cols), BK=32.
// global_load_lds staging, XOR granule swizzle, double-buffer, 1 barrier/step.
__global__ __launch_bounds__(256, 3) void gemm1_kernel(
    const unsigned short* __restrict__ xn_b,
    const unsigned short* __restrict__ w1t,   // [E][2H][D] bf16
    const int* __restrict__ list,
    const int* __restrict__ counts,
    unsigned short* __restrict__ act_b)
{
    const int e   = blockIdx.z;
    const int cnt = counts[e];
    const int m0  = blockIdx.y * 128;
    if (m0 >= cnt) return;
    const int c0  = blockIdx.x * 64;          // act cols

    __shared__ __attribute__((aligned(128))) unsigned char lds[2][16384];
    __shared__ int pairL[128];

    const int tid  = threadIdx.x;
    const int lane = tid & 63;
    const int wv   = tid >> 6;
    const int wr   = wv >> 1, wc = wv & 1;

    if (tid < 128) {
        int r = m0 + tid;
        pairL[tid] = (r < cnt) ? list[e * N_ + r] : -1;
    }
    __syncthreads();

    // per-thread staging source addresses (granule pre-swizzled: rule #21)
    const int srow = tid >> 2;                // 0..63
    const int glin = tid & 3;
    const unsigned short* aAddr[2];
    #pragma unroll
    for (int i = 0; i < 2; ++i) {
        int row = i * 64 + srow;
        int p   = pairL[row];
        int tok = (p >= 0) ? (p >> 1) : 0;
        int gsrc = glin ^ ((row >> 1) & 3);
        aAddr[i] = xn_b + (size_t)tok * D_ + gsrc * 8;
    }
    const unsigned short* w1te = w1t + (size_t)e * (size_t)D_ * H2_;
    const int gsrcB = glin ^ ((srow >> 1) & 3);
    const unsigned short* bxAddr = w1te + (size_t)(c0 + srow) * D_ + gsrcB * 8;
    const unsigned short* bgAddr = w1te + (size_t)(H_ + c0 + srow) * D_ + gsrcB * 8;

    const int wvOff = wv * 1024;              // wave-uniform LDS slice
    const int gsw = (((lane >> 4) ^ ((lane >> 1) & 3)) << 4);  // swizzled granule byte
    const int fr  = lane & 15;
    const int fq  = lane >> 4;

    f32x4 accx[4][2], accg[4][2];
    #pragma unroll
    for (int m = 0; m < 4; ++m)
        #pragma unroll
        for (int n = 0; n < 2; ++n) {
            accx[m][n] = (f32x4){0.f, 0.f, 0.f, 0.f};
            accg[m][n] = (f32x4){0.f, 0.f, 0.f, 0.f};
        }

    // prologue: stage k=0 into buf0  (A:0..8K | Bx:8K..12K | Bg:12K..16K)
    {
        unsigned char* b = &lds[0][0];
        gl16(aAddr[0], b + wvOff);
        gl16(aAddr[1], b + 4096 + wvOff);
        gl16(bxAddr,   b + 8192 + wvOff);
        gl16(bgAddr,   b + 12288 + wvOff);
    }
    __syncthreads();

    int cur = 0;
    for (int t = 0; t < D_ / 32; ++t) {
        if (t + 1 < D_ / 32) {                // issue next-tile async loads
            const int kn = (t + 1) * 32;
            unsigned char* b = &lds[cur ^ 1][0];
            gl16(aAddr[0] + kn, b + wvOff);
            gl16(aAddr[1] + kn, b + 4096 + wvOff);
            gl16(bxAddr   + kn, b + 8192 + wvOff);
            gl16(bgAddr   + kn, b + 12288 + wvOff);
        }
        const unsigned char* bb = &lds[cur][0];
        bf16x8 af[4], bx[2], bg[2];
        #pragma unroll
        for (int m = 0; m < 4; ++m)
            af[m] = *(const bf16x8*)(bb + (wr * 64 + m * 16 + fr) * 64 + gsw);
        #pragma unroll
        for (int n = 0; n < 2; ++n) {
            bx[n] = *(const bf16x8*)(bb + 8192  + (wc * 32 + n * 16 + fr) * 64 + gsw);
            bg[n] = *(const bf16x8*)(bb + 12288 + (wc * 32 + n * 16 + fr) * 64 + gsw);
        }
        #pragma unroll
        for (int m = 0; m < 4; ++m)
            #pragma unroll
            for (int n = 0; n < 2; ++n) {
                accx[m][n] = __builtin_amdgcn_mfma_f32_16x16x32_bf16(af[m], bx[n], accx[m][n], 0, 0, 0);
                accg[m][n] = __builtin_amdgcn_mfma_f32_16x16x32_bf16(af[m], bg[n], accg[m][n], 0, 0, 0);
            }
        __syncthreads();                      // drains vmcnt -> other buf staged
        cur ^= 1;
    }

    #pragma unroll
    for (int m = 0; m < 4; ++m) {
        #pragma unroll
        for (int j = 0; j < 4; ++j) {
            int rowt = wr * 64 + m * 16 + fq * 4 + j;
            if (m0 + rowt < cnt) {
                int pair = pairL[rowt];
                unsigned short* arow = act_b + (size_t)pair * H_ + c0 + wc * 32 + fr;
                #pragma unroll
                for (int n = 0; n < 2; ++n) {
                    float hx = accx[m][n][j];
                    float hg = accg[m][n][j];
                    arow[n * 16] = f2bf(gelu_exact(hg) * hx);
                }
            }
        }
    }
}

// ==================== Kernel 3: GEMM2 (MFMA bf16) + scatter =================
// Block: 128 rows x 128 D-cols, BK=32, K(=H) split in 2; atomic epilogue.
__global__ __launch_bounds__(256, 3) void gemm2_kernel(
    const unsigned short* __restrict__ act_b,
    const unsigned short* __restrict__ w2t,   // [E][D][H] bf16
    const int* __restrict__ list,
    const int* __restrict__ counts,
    const float* __restrict__ w_pair,
    float* __restrict__ out)
{
    const int z = blockIdx.z;
    const int e = z >> 1, ks = z & 1;
    const int cnt = counts[e];
    const int m0  = blockIdx.y * 128;
    if (m0 >= cnt) return;
    const int c0  = blockIdx.x * 128;
    const int kbase = ks * (H_ / 2);

    __shared__ __attribute__((aligned(128))) unsigned char lds[2][16384];
    __shared__ int   pairL[128];
    __shared__ float wgtL[128];

    const int tid  = threadIdx.x;
    const int lane = tid & 63;
    const int wv   = tid >> 6;
    const int wr   = wv >> 1, wc = wv & 1;

    if (tid < 128) {
        int r = m0 + tid;
        int p = (r < cnt) ? list[e * N_ + r] : -1;
        pairL[tid] = p;
        wgtL[tid]  = (p >= 0) ? w_pair[p] : 0.f;
    }
    __syncthreads();

    const int srow = tid >> 2;
    const int glin = tid & 3;
    const unsigned short* aAddr[2];
    const unsigned short* bAddr[2];
    const unsigned short* w2te = w2t + (size_t)e * (size_t)D_ * H_;
    #pragma unroll
    for (int i = 0; i < 2; ++i) {
        int row = i * 64 + srow;
        int gsrc = glin ^ ((row >> 1) & 3);
        int p = pairL[row];
        aAddr[i] = act_b + (size_t)((p >= 0) ? p : 0) * H_ + kbase + gsrc * 8;
        bAddr[i] = w2te + (size_t)(c0 + row) * H_ + kbase + gsrc * 8;
    }

    const int wvOff = wv * 1024;
    const int gsw = (((lane >> 4) ^ ((lane >> 1) & 3)) << 4);
    const int fr  = lane & 15;
    const int fq  = lane >> 4;

    f32x4 acc[4][4];
    #pragma unroll
    for (int m = 0; m < 4; ++m)
        #pragma unroll
        for (int n = 0; n < 4; ++n) acc[m][n] = (f32x4){0.f, 0.f, 0.f, 0.f};

    {
        unsigned char* b = &lds[0][0];
        gl16(aAddr[0], b + wvOff);
        gl16(aAddr[1], b + 4096 + wvOff);
        gl16(bAddr[0], b + 8192 + wvOff);
        gl16(bAddr[1], b + 12288 + wvOff);
    }
    __syncthreads();

    int cur = 0;
    for (int t = 0; t < (H_ / 2) / 32; ++t) {
        if (t + 1 < (H_ / 2) / 32) {
            const int kn = (t + 1) * 32;
            unsigned char* b = &lds[cur ^ 1][0];
            gl16(aAddr[0] + kn, b + wvOff);
            gl16(aAddr[1] + kn, b + 4096 + wvOff);
            gl16(bAddr[0] + kn, b + 8192 + wvOff);
            gl16(bAddr[1] + kn, b + 12288 + wvOff);
        }
        const unsigned char* bb = &lds[cur][0];
        bf16x8 af[4], bf_[4];
        #pragma unroll
        for (int m = 0; m < 4; ++m)
            af[m] = *(const bf16x8*)(bb + (wr * 64 + m * 16 + fr) * 64 + gsw);
        #pragma unroll
        for (int n = 0; n < 4; ++n)
            bf_[n] = *(const bf16x8*)(bb + 8192 + (wc * 64 + n * 16 + fr) * 64 + gsw);
        #pragma unroll
        for (int m = 0; m < 4; ++m)
            #pragma unroll
            for (int n = 0; n < 4; ++n)
                acc[m][n] = __builtin_amdgcn_mfma_f32_16x16x32_bf16(af[m], bf_[n], acc[m][n], 0, 0, 0);
        __syncthreads();
        cur ^= 1;
    }

    #pragma unroll
    for (int m = 0; m < 4; ++m) {
        #pragma unroll
        for (int j = 0; j < 4; ++j) {
            int rowt = wr * 64 + m * 16 + fq * 4 + j;
            if (m0 + rowt < cnt) {
                int p = pairL[rowt];
                int token = p >> 1;
                float w = wgtL[rowt];
                float* orow = out + (size_t)token * D_ + c0 + wc * 64 + fr;
                #pragma unroll
                for (int n = 0; n < 4; ++n)
                    atomicAdd(&orow[n * 16], w * acc[m][n][j]);
            }
        }
    }
}

// =============================== launcher ===================================
extern "C" void kernel_launch(void* const* d_in, const int* in_sizes, int n_in,
                              void* d_out, int out_size, void* d_ws, size_t ws_size,
                              hipStream_t stream)
{
    const float* x      = (const float*)d_in[0];
    const float* ln_w   = (const float*)d_in[1];
    const float* ln_b   = (const float*)d_in[2];
    const float* gate_w = (const float*)d_in[3];
    const float* w1     = (const float*)d_in[4];
    const float* w2     = (const float*)d_in[5];
    float* out = (float*)d_out;

    unsigned char* w = (unsigned char*)d_ws;
    size_t off = 0;
    auto alloc = [&](size_t bytes) -> void* {
        void* p = w + off;
        off += (bytes + 255) & ~(size_t)255;
        return p;
    };
    unsigned short* xn_b  = (unsigned short*)alloc((size_t)N_ * D_ * 2);
    unsigned short* act_b = (unsigned short*)alloc((size_t)N_ * 2 * H_ * 2);
    float* w_pair = (float*)alloc((size_t)N_ * 2 * 4);
    int*   lists  = (int*)alloc((size_t)E_ * N_ * 4);
    int*   counts = (int*)alloc(256);
    unsigned short* w1t = (unsigned short*)alloc((size_t)E_ * D_ * H2_ * 2);
    unsigned short* w2t = (unsigned short*)alloc((size_t)E_ * H_ * D_ * 2);
    (void)off;

    hipMemsetAsync(counts, 0, 256, stream);

    wprep_kernel<<<12288, 256, 0, stream>>>(w1, w2, w1t, w2t);

    ln_router_kernel<<<N_, 256, 0, stream>>>(x, ln_w, ln_b, gate_w, out, xn_b,
                                             w_pair, lists, counts);

    gemm1_kernel<<<dim3(H_ / 64, 16, E_), 256, 0, stream>>>(
        xn_b, w1t, lists, counts, act_b);

    gemm2_kernel<<<dim3(D_ / 128, 16, E_ * 2), 256, 0, stream>>>(
        act_b, w2t, lists, counts, w_pair, out);
}